// Round 1
// baseline (315.359 us; speedup 1.0000x reference)
//
#include <hip/hip_runtime.h>

// WARP loss: B=4096 rows, Y=10000 labels, T=128 negative-candidate trials.
// input [B,Y] f32, target [B,Y] f32 (exactly one-hot), neg_candidates [B,T] i32.
// out[0] = sum over rows of log((Y-1)/num_trials) * (1 - s_pos + s_neg),
// where num_trials = 1 + first t with 1 + s_neg_t - s_pos >= 0 (0 if none).

constexpr int Yc = 10000;
constexpr int Tc = 128;

__global__ __launch_bounds__(256) void warp_loss_kernel(
        const float* __restrict__ input,
        const float* __restrict__ target,
        const int*   __restrict__ neg,
        float* __restrict__ out) {
    const int row = blockIdx.x;
    const int tid = threadIdx.x;

    __shared__ int   sh_pos_idx;   // index of the one-hot positive label
    __shared__ int   sh_first;     // first accepted trial index (T if none)
    __shared__ float sh_spos;      // positive score

    if (tid == 0) sh_first = Tc;

    // ---- find the one-hot index: value > 0.5 at exactly one position ----
    // Y = 10000 -> 2500 float4 per row; row byte offset 40000 is 16B-aligned.
    const float4* trow = reinterpret_cast<const float4*>(target + (size_t)row * Yc);
    int found_idx = -1;
    #pragma unroll 4
    for (int i = tid; i < Yc / 4; i += 256) {
        float4 v = trow[i];
        if (v.x > 0.5f) found_idx = 4 * i + 0;
        if (v.y > 0.5f) found_idx = 4 * i + 1;
        if (v.z > 0.5f) found_idx = 4 * i + 2;
        if (v.w > 0.5f) found_idx = 4 * i + 3;
    }
    if (found_idx >= 0) sh_pos_idx = found_idx;  // exactly one writer per block
    __syncthreads();

    if (tid == 0) sh_spos = input[(size_t)row * Yc + sh_pos_idx];
    __syncthreads();
    const float s_pos = sh_spos;

    // ---- rejection sampling: first t with 1 + s_neg - s_pos >= 0 ----
    if (tid < Tc) {
        int   c = neg[row * Tc + tid];
        float s = input[(size_t)row * Yc + c];
        if (1.0f + s - s_pos >= 0.0f) atomicMin(&sh_first, tid);
    }
    __syncthreads();

    if (tid == 0 && sh_first < Tc) {
        int   nt    = sh_first + 1;
        float L     = logf((float)((Yc - 1) / nt));      // floor-divide then log
        int   c     = neg[row * Tc + sh_first];
        float s_neg = input[(size_t)row * Yc + c];
        atomicAdd(out, L * (1.0f - s_pos + s_neg));
    }
}

extern "C" void kernel_launch(void* const* d_in, const int* in_sizes, int n_in,
                              void* d_out, int out_size, void* d_ws, size_t ws_size,
                              hipStream_t stream) {
    const float* input  = (const float*)d_in[0];
    const float* target = (const float*)d_in[1];
    const int*   neg    = (const int*)d_in[2];
    float* out = (float*)d_out;

    const int B = in_sizes[2] / Tc;  // 4096

    // Harness re-poisons d_out to 0xAA before every timed replay: zero it here.
    hipMemsetAsync(out, 0, sizeof(float), stream);
    warp_loss_kernel<<<B, 256, 0, stream>>>(input, target, neg, out);
}